// Round 14
// baseline (56.580 us; speedup 1.0000x reference)
//
#include <hip/hip_runtime.h>
#include <math.h>

#define NBS 2
#define NPTS 4096
#define HH 64
#define WW 192
#define HW (HH*WW)        // 12288
#define NC 64
#define GX 24             // cells in x (8 px each)
#define GY 8              // cells in y
#define NCELL (GX*GY)     // 192
#define CSB 256           // cellStart stride per batch

#define FBIG 3.0e38f
#define IBIG 0x7FFFFFFF

// ---------------- K0: bin points (blocks 0-1) + transpose feat_3d -----------
__global__ __launch_bounds__(256) void k0_prep(
    const float* __restrict__ uv, const float* __restrict__ f3d,
    float* __restrict__ f3dT, float4* __restrict__ binned,
    int* __restrict__ cellStart) {
#pragma clang fp contract(off)
  int bid = blockIdx.x;
  int t = threadIdx.x;
  if (bid < 2) {
    // counting-sort bin for batch b (single block per batch)
    int b = bid;
    __shared__ int hist[NCELL + 1];
    __shared__ int cur[NCELL];
    if (t <= NCELL) hist[t] = 0;
    __syncthreads();
    const float* u0p = uv + (size_t)b * 2 * NPTS;
    const float* u1p = u0p + NPTS;
    for (int n = t; n < NPTS; n += 256) {
      float u0 = u0p[n], u1 = u1p[n];
      int cxp = min((int)(u0 * 0.125f), GX - 1);   // *0.125f exact (pow2)
      int cyp = min((int)(u1 * 0.125f), GY - 1);
      atomicAdd(&hist[cyp * GX + cxp + 1], 1);
    }
    __syncthreads();
    // parallel Hillis-Steele inclusive scan over hist[0..NCELL]
    for (int off = 1; off <= NCELL; off <<= 1) {
      int v = 0;
      if (t <= NCELL && t >= off) v = hist[t - off];
      __syncthreads();
      if (t <= NCELL && t >= off) hist[t] += v;
      __syncthreads();
    }
    if (t < NCELL) cur[t] = hist[t];
    if (t <= NCELL) cellStart[b * CSB + t] = hist[t];
    __syncthreads();
    for (int n = t; n < NPTS; n += 256) {
      float u0 = u0p[n], u1 = u1p[n];
      // golden rounding: uu = rnd(rnd(u0^2)+rnd(u1^2)); contract(off) => no fma
      float s0 = u0 * u0;
      float s1 = u1 * u1;
      float uu = s0 + s1;
      int cxp = min((int)(u0 * 0.125f), GX - 1);
      int cyp = min((int)(u1 * 0.125f), GY - 1);
      int pos = atomicAdd(&cur[cyp * GX + cxp], 1);
      binned[(size_t)b * NPTS + pos] =
          make_float4(u0 + u0, u1 + u1, uu, __int_as_float(n));
    }
  } else {
    // transpose 64n x 32c half-tile: bb in [0,256)
    int bb = bid - 2;
    int b = bb >> 7;                       // batch
    int half = (bb >> 6) & 1;              // channel half
    int nt = (bb & 63) << 6;               // n tile base
    __shared__ float tile[32][65];
    int n_in = t & 63;
    int r0 = t >> 6;                       // 0..3
    const float* src = f3d + (size_t)b * NC * NPTS + (size_t)half * 32 * NPTS;
#pragma unroll
    for (int r = 0; r < 8; ++r) {
      int c = r0 + (r << 2);               // 0..31
      tile[c][n_in] = src[(size_t)c * NPTS + nt + n_in];
    }
    __syncthreads();
    float* dst = f3dT + ((size_t)b * NPTS + nt) * NC + half * 32;
    int c_out = t & 31;                    // 0..31
    int n0 = t >> 5;                       // 0..7
#pragma unroll
    for (int r = 0; r < 8; ++r) {
      int n = n0 + (r << 3);
      dst[(size_t)n * NC + c_out] = tile[c_out][n];
    }
  }
}

// ---------------- K_MAIN: fused binned 3-NN + MLP + out-projection ----------
// 8px cells (R8-measured best KNN geometry). Block = 16 queries x 16 lanes,
// mapping constant through KNN -> coop-h1 -> score (top-3 carried in regs,
// no sidx LDS). 2 barriers. Scan insert dup-free; merge insert dup-safe.
__global__ __launch_bounds__(256) void k_main(
    const float4* __restrict__ binned, const int* __restrict__ cellStart,
    const float* __restrict__ uv, const float* __restrict__ f3dT,
    const float* __restrict__ w1, const float* __restrict__ b1,
    const float* __restrict__ w2, const float* __restrict__ b2,
    const float* __restrict__ w_out, const float* __restrict__ b_out,
    float* __restrict__ out) {
#pragma clang fp contract(off)
  int t = threadIdx.x;
  int b = blockIdx.y;
  int Q = t >> 4;                      // query slot 0..15
  int j = t & 15;                      // splitter / h1-unit / channel lane
  int qi = blockIdx.x * 16 + Q;
  int x = qi % WW, y = qi / WW;
  float xf = (float)x, yf = (float)y;
  float gg = xf * xf + yf * yf;        // exact small ints

  __shared__ float sh1f[16 * 52];      // h1[3][16] per query
  __shared__ float fin[16][68];        // row stride 272 B

  // ===== phase 1: KNN (16 lanes/query) =====
  float v0 = FBIG, v1 = FBIG, v2 = FBIG;
  int i0 = IBIG, i1 = IBIG, i2 = IBIG;
  {
    int cx = x >> 3, cy = y >> 3;
    const float4* __restrict__ pts = binned + (size_t)b * NPTS;
    const int* __restrict__ cs = cellStart + b * CSB;

    // dup-free lex (d,idx) sorted insert — scan candidates are distinct
    auto insS = [&](float d, int gi) {
      bool lt2 = (d < v2) || (d == v2 && gi < i2);
      bool lt1 = (d < v1) || (d == v1 && gi < i1);
      bool lt0 = (d < v0) || (d == v0 && gi < i0);
      i2 = lt1 ? i1 : (lt2 ? gi : i2);
      v2 = lt1 ? v1 : (lt2 ? d : v2);
      i1 = lt0 ? i0 : (lt1 ? gi : i1);
      v1 = lt0 ? v0 : (lt1 ? d : v1);
      i0 = lt0 ? gi : i0;
      v0 = lt0 ? d : v0;
    };
    // dup-safe variant for cross-lane merges (idempotent under repeats)
    auto insM = [&](float d, int gi) {
      bool dup = (gi == i0) || (gi == i1) || (gi == i2);
      bool lt2 = !dup && ((d < v2) || (d == v2 && gi < i2));
      bool lt1 = !dup && ((d < v1) || (d == v1 && gi < i1));
      bool lt0 = !dup && ((d < v0) || (d == v0 && gi < i0));
      i2 = lt1 ? i1 : (lt2 ? gi : i2);
      v2 = lt1 ? v1 : (lt2 ? d : v2);
      i1 = lt0 ? i0 : (lt1 ? gi : i1);
      v1 = lt0 ? v0 : (lt1 ? d : v1);
      i0 = lt0 ? gi : i0;
      v0 = lt0 ? d : v0;
    };
    auto scanRow = [&](int ry, int cA, int cB) {
      int s = cs[ry * GX + cA];
      int e = cs[ry * GX + cB + 1];    // cells row-contiguous -> one segment
      for (int n = s + j; n < e; n += 16) {
        float4 p = pts[n];
        // golden: d2 = rnd(gg+uu) - 2*fma(y,u1, rnd(x*u0)); x2 pre-scaled
        float d = (gg + p.z) - __builtin_fmaf(yf, p.y, xf * p.x);
        insS(d, __float_as_int(p.w));
      }
    };
    auto mergeAll = [&]() {
#pragma unroll
      for (int m = 1; m <= 8; m <<= 1) {
        float ov0 = __shfl_xor(v0, m), ov1 = __shfl_xor(v1, m),
              ov2 = __shfl_xor(v2, m);
        int oi0 = __shfl_xor(i0, m), oi1 = __shfl_xor(i1, m),
            oi2 = __shfl_xor(i2, m);
        insM(ov0, oi0); insM(ov1, oi1); insM(ov2, oi2);
      }
    };

    int cxL = max(cx - 1, 0), cxH = min(cx + 1, GX - 1);
    int cyL = max(cy - 1, 0), cyH = min(cy + 1, GY - 1);
    for (int ry = cyL; ry <= cyH; ++ry) scanRow(ry, cxL, cxH);
    mergeAll();

    // ring expansion: statistically never taken at 8px (P ~ e^-67), but
    // exactness-preserving; computed-d2 skew bound <= 0.1 << 4.0 slack.
    while (true) {
      bool fullDom = (cxL == 0 && cxH == GX - 1 && cyL == 0 && cyH == GY - 1);
      float dL = (cxL > 0) ? (xf - (float)(cxL * 8)) : FBIG;
      float dR = (cxH < GX - 1) ? ((float)((cxH + 1) * 8) - xf) : FBIG;
      float dB = (cyL > 0) ? (yf - (float)(cyL * 8)) : FBIG;
      float dT = (cyH < GY - 1) ? ((float)((cyH + 1) * 8) - yf) : FBIG;
      float dmin = fminf(fminf(dL, dR), fminf(dB, dT));
      if (fullDom || (v2 < dmin * dmin - 4.0f)) break;
      int nxL = max(cxL - 1, 0), nxH = min(cxH + 1, GX - 1);
      int nyL = max(cyL - 1, 0), nyH = min(cyH + 1, GY - 1);
      for (int ry = nyL; ry <= nyH; ++ry) {
        if (ry < cyL || ry > cyH) scanRow(ry, nxL, nxH);
        else {
          if (nxL < cxL) scanRow(ry, nxL, cxL - 1);
          if (nxH > cxH) scanRow(ry, cxH + 1, nxH);
        }
      }
      cxL = nxL; cxH = nxH; cyL = nyL; cyH = nyH;
      mergeAll();
    }
  }
  // all 16 lanes of query Q hold the top-3 (i0,i1,i2) in registers

  // ===== phase 1.5: coop h1 — lane j computes h1[k][j] for its query ======
  {
    float wa = w1[j * 3 + 0], wb = w1[j * 3 + 1], wc = w1[j * 3 + 2];
    float bo = b1[j];
    int idx[3] = {i0, i1, i2};
#pragma unroll
    for (int k = 0; k < 3; ++k) {
      int i = idx[k];
      float u0 = uv[(size_t)b * 2 * NPTS + i];
      float u1 = uv[(size_t)b * 2 * NPTS + NPTS + i];
      float dx = u0 - xf;
      float dy = u1 - yf;
      float nrm = sqrtf(__builtin_fmaf(dx, dx, dy * dy));
      float h = fmaf(wa, dx, fmaf(wb, dy, fmaf(wc, nrm, bo)));
      sh1f[Q * 52 + k * 16 + j] = (h >= 0.0f) ? h : 0.1f * h;
    }
  }
  __syncthreads();

  // ===== phase 2: score + weighted sum — lane j: channels [4j,4j+4) ========
  {
    float h1a[3][16];
    {
      const float4* h4 = (const float4*)(sh1f + Q * 52);
#pragma unroll
      for (int i = 0; i < 12; ++i) {
        float4 v = h4[i];                // broadcast within query group
        int k = i >> 2, oo = (i & 3) * 4;
        h1a[k][oo + 0] = v.x; h1a[k][oo + 1] = v.y;
        h1a[k][oo + 2] = v.z; h1a[k][oo + 3] = v.w;
      }
    }
    // 16 lanes x float4 = full 256B row per neighbor: coalesced
    float4 f0 = *(const float4*)(f3dT + ((size_t)b * NPTS + i0) * NC + j * 4);
    float4 f1 = *(const float4*)(f3dT + ((size_t)b * NPTS + i1) * NC + j * 4);
    float4 f2 = *(const float4*)(f3dT + ((size_t)b * NPTS + i2) * NC + j * 4);
    float fa[4] = {f0.x, f0.y, f0.z, f0.w};
    float fb[4] = {f1.x, f1.y, f1.z, f1.w};
    float fc[4] = {f2.x, f2.y, f2.z, f2.w};
    float res[4];
#pragma unroll
    for (int cc = 0; cc < 4; ++cc) {
      int c = j * 4 + cc;
      float bias = b2[c];
      float s0 = bias, s1 = bias, s2 = bias;
      const float4* w2r = (const float4*)(w2 + c * 16);
#pragma unroll
      for (int o4 = 0; o4 < 4; ++o4) {
        float4 wv = w2r[o4];
        float wvs[4] = {wv.x, wv.y, wv.z, wv.w};
#pragma unroll
        for (int oo = 0; oo < 4; ++oo) {
          int oi = o4 * 4 + oo;
          s0 = fmaf(wvs[oo], h1a[0][oi], s0);
          s1 = fmaf(wvs[oo], h1a[1][oi], s1);
          s2 = fmaf(wvs[oo], h1a[2][oi], s2);
        }
      }
      float g0 = 1.0f / (1.0f + __expf(-s0));
      float g1 = 1.0f / (1.0f + __expf(-s1));
      float g2 = 1.0f / (1.0f + __expf(-s2));
      res[cc] = fmaf(g0, fa[cc], fmaf(g1, fb[cc], g2 * fc[cc]));
    }
    *(float4*)(&fin[Q][j * 4]) = make_float4(res[0], res[1], res[2], res[3]);
  }
  __syncthreads();

  // ===== phase B: out-projection, remapped for coalesced writes ============
  {
    int qb = t & 15;
    int cgb = t >> 4;
    int q = blockIdx.x * 16 + qb;
    int o0 = cgb * 4;
    float acc[4];
#pragma unroll
    for (int jj = 0; jj < 4; ++jj) acc[jj] = b_out[o0 + jj];
    const float4* finq = (const float4*)(&fin[qb][0]);
#pragma unroll 4
    for (int c4 = 0; c4 < 16; ++c4) {
      float4 f = finq[c4];
#pragma unroll
      for (int jj = 0; jj < 4; ++jj) {
        float4 wv = *(const float4*)(w_out + (o0 + jj) * 64 + c4 * 4);
        acc[jj] = fmaf(wv.x, f.x,
                  fmaf(wv.y, f.y,
                  fmaf(wv.z, f.z,
                  fmaf(wv.w, f.w, acc[jj]))));
      }
    }
    float* dst = out + ((size_t)(b * 64 + o0)) * HW + q;
#pragma unroll
    for (int jj = 0; jj < 4; ++jj) {
      float v = acc[jj];
      dst[(size_t)jj * HW] = (v >= 0.0f) ? v : 0.1f * v;
    }
  }
}

extern "C" void kernel_launch(void* const* d_in, const int* in_sizes, int n_in,
                              void* d_out, int out_size, void* d_ws, size_t ws_size,
                              hipStream_t stream) {
  const float* uv   = (const float*)d_in[0];
  // d_in[1] = feat_2d : values unused by the reference (shape only)
  const float* f3d  = (const float*)d_in[2];
  const float* w1   = (const float*)d_in[3];
  const float* b1   = (const float*)d_in[4];
  const float* w2   = (const float*)d_in[5];
  const float* b2   = (const float*)d_in[6];
  const float* wout = (const float*)d_in[7];
  const float* bout = (const float*)d_in[8];
  float* out = (float*)d_out;

  char* ws = (char*)d_ws;
  float*  f3dT      = (float*)(ws);             // 2*4096*64*4 = 2097152 B
  float4* binned    = (float4*)(ws + 2097152);  // 2*4096*16   = 131072 B
  int*    cellStart = (int*)(ws + 2228224);     // 2*256*4     = 2048 B
                                                // total ≈ 2.23 MB

  hipLaunchKernelGGL(k0_prep, dim3(258), dim3(256), 0, stream,
                     uv, f3d, f3dT, binned, cellStart);
  hipLaunchKernelGGL(k_main, dim3(HW / 16, NBS), dim3(256), 0, stream,
                     (const float4*)binned, (const int*)cellStart,
                     uv, f3dT, w1, b1, w2, b2, wout, bout, out);
}

// Round 15
// 47.192 us; speedup vs baseline: 1.1989x; 1.1989x over previous
//
#include <hip/hip_runtime.h>
#include <math.h>

#define NBS 2
#define NPTS 4096
#define HH 64
#define WW 192
#define HW (HH*WW)        // 12288
#define NC 64
#define GX 48             // cells in x (4 px each)
#define GY 16             // cells in y
#define NCELL (GX*GY)     // 768
#define CSB 1024          // cellStart stride per batch

#define FBIG 3.0e38f
#define IBIG 0x7FFFFFFF

// ---------------- K0: bin points (blocks 0-1) + transpose feat_3d -----------
__global__ __launch_bounds__(256) void k0_prep(
    const float* __restrict__ uv, const float* __restrict__ f3d,
    float* __restrict__ f3dT, float4* __restrict__ binned,
    int* __restrict__ cellStart) {
#pragma clang fp contract(off)
  int bid = blockIdx.x;
  int t = threadIdx.x;
  if (bid < 2) {
    // counting-sort bin for batch b (single block per batch)
    int b = bid;
    __shared__ int hist[NCELL];
    __shared__ int cum[NCELL];
    __shared__ int cur[NCELL];
    for (int c = t; c < NCELL; c += 256) hist[c] = 0;
    __syncthreads();
    const float* u0p = uv + (size_t)b * 2 * NPTS;
    const float* u1p = u0p + NPTS;
    for (int n = t; n < NPTS; n += 256) {
      float u0 = u0p[n], u1 = u1p[n];
      int cxp = min((int)(u0 * 0.25f), GX - 1);   // *0.25f exact (pow2)
      int cyp = min((int)(u1 * 0.25f), GY - 1);
      atomicAdd(&hist[cyp * GX + cxp], 1);
    }
    __syncthreads();
    // single-wave inclusive scan: 12 chunks of 64 + running carry
    if (t < 64) {
      int carry = 0;
#pragma unroll
      for (int ck = 0; ck < NCELL / 64; ++ck) {
        int v = hist[ck * 64 + t];
#pragma unroll
        for (int off = 1; off < 64; off <<= 1) {
          int u = __shfl_up(v, off);
          if (t >= off) v += u;
        }
        cum[ck * 64 + t] = v + carry;
        carry += __shfl(v, 63);
      }
    }
    __syncthreads();
    if (t == 0) cellStart[b * CSB] = 0;
    for (int c = t; c < NCELL; c += 256) {
      cellStart[b * CSB + c + 1] = cum[c];
      cur[c] = cum[c] - hist[c];            // exclusive start
    }
    __syncthreads();
    for (int n = t; n < NPTS; n += 256) {
      float u0 = u0p[n], u1 = u1p[n];
      // golden rounding: uu = rnd(rnd(u0^2)+rnd(u1^2)); contract(off) => no fma
      float s0 = u0 * u0;
      float s1 = u1 * u1;
      float uu = s0 + s1;
      int cxp = min((int)(u0 * 0.25f), GX - 1);
      int cyp = min((int)(u1 * 0.25f), GY - 1);
      int pos = atomicAdd(&cur[cyp * GX + cxp], 1);
      binned[(size_t)b * NPTS + pos] =
          make_float4(u0 + u0, u1 + u1, uu, __int_as_float(n));
    }
  } else {
    // transpose 64n x 32c half-tile: bb in [0,256)
    int bb = bid - 2;
    int b = bb >> 7;                       // batch
    int half = (bb >> 6) & 1;              // channel half
    int nt = (bb & 63) << 6;               // n tile base
    __shared__ float tile[32][65];
    int n_in = t & 63;
    int r0 = t >> 6;                       // 0..3
    const float* src = f3d + (size_t)b * NC * NPTS + (size_t)half * 32 * NPTS;
#pragma unroll
    for (int r = 0; r < 8; ++r) {
      int c = r0 + (r << 2);               // 0..31
      tile[c][n_in] = src[(size_t)c * NPTS + nt + n_in];
    }
    __syncthreads();
    float* dst = f3dT + ((size_t)b * NPTS + nt) * NC + half * 32;
    int c_out = t & 31;                    // 0..31
    int n0 = t >> 5;                       // 0..7
#pragma unroll
    for (int r = 0; r < 8; ++r) {
      int n = n0 + (r << 3);
      dst[(size_t)n * NC + c_out] = tile[c_out][n];
    }
  }
}

// ---------------- K_MAIN: fused binned 3-NN + MLP + out-projection ----------
// The 48.1 µs configuration (Round-11 bench), verbatim, except the SCAN
// insert drops the dup-check (scan candidates are distinct; only cross-lane
// merges need the dup-safe variant — R10 fix retained there).
__global__ __launch_bounds__(256) void k_main(
    const float4* __restrict__ binned, const int* __restrict__ cellStart,
    const float* __restrict__ uv, const float* __restrict__ f3dT,
    const float* __restrict__ w1, const float* __restrict__ b1,
    const float* __restrict__ w2, const float* __restrict__ b2,
    const float* __restrict__ w_out, const float* __restrict__ b_out,
    float* __restrict__ out) {
#pragma clang fp contract(off)
  int t = threadIdx.x;
  int b = blockIdx.y;

  __shared__ int sidx[16][4];
  __shared__ float sh1f[16 * 52];  // h1[3][16] per query, 52-float row
  __shared__ float fin[16][68];    // row stride 272 B

  // ===== phase 1: KNN =====
  {
    int Q = t >> 4;                      // query slot 0..15
    int j = t & 15;                      // splitter lane
    int qi = blockIdx.x * 16 + Q;
    int x = qi % WW, y = qi / WW;
    float xf = (float)x, yf = (float)y;
    float gg = xf * xf + yf * yf;        // exact small ints
    int cx = x >> 2, cy = y >> 2;

    const float4* __restrict__ pts = binned + (size_t)b * NPTS;
    const int* __restrict__ cs = cellStart + b * CSB;

    float v0 = FBIG, v1 = FBIG, v2 = FBIG;
    int i0 = IBIG, i1 = IBIG, i2 = IBIG;

    // dup-free lex (d,idx) sorted insert — scan candidates are distinct
    auto insS = [&](float d, int gi) {
      bool lt2 = (d < v2) || (d == v2 && gi < i2);
      bool lt1 = (d < v1) || (d == v1 && gi < i1);
      bool lt0 = (d < v0) || (d == v0 && gi < i0);
      i2 = lt1 ? i1 : (lt2 ? gi : i2);
      v2 = lt1 ? v1 : (lt2 ? d : v2);
      i1 = lt0 ? i0 : (lt1 ? gi : i1);
      v1 = lt0 ? v0 : (lt1 ? d : v1);
      i0 = lt0 ? gi : i0;
      v0 = lt0 ? d : v0;
    };
    // dup-safe variant for cross-lane merges (idempotent under repeats)
    auto insM = [&](float d, int gi) {
      bool dup = (gi == i0) || (gi == i1) || (gi == i2);
      bool lt2 = !dup && ((d < v2) || (d == v2 && gi < i2));
      bool lt1 = !dup && ((d < v1) || (d == v1 && gi < i1));
      bool lt0 = !dup && ((d < v0) || (d == v0 && gi < i0));
      i2 = lt1 ? i1 : (lt2 ? gi : i2);
      v2 = lt1 ? v1 : (lt2 ? d : v2);
      i1 = lt0 ? i0 : (lt1 ? gi : i1);
      v1 = lt0 ? v0 : (lt1 ? d : v1);
      i0 = lt0 ? gi : i0;
      v0 = lt0 ? d : v0;
    };
    auto scanRow = [&](int ry, int cA, int cB) {
      int s = cs[ry * GX + cA];
      int e = cs[ry * GX + cB + 1];      // cells row-contiguous -> one segment
      for (int n = s + j; n < e; n += 16) {
        float4 p = pts[n];
        // golden: d2 = rnd(gg+uu) - 2*fma(y,u1, rnd(x*u0)); x2 pre-scaled
        float d = (gg + p.z) - __builtin_fmaf(yf, p.y, xf * p.x);
        insS(d, __float_as_int(p.w));
      }
    };
    auto mergeAll = [&]() {
#pragma unroll
      for (int m = 1; m <= 8; m <<= 1) {
        float ov0 = __shfl_xor(v0, m), ov1 = __shfl_xor(v1, m),
              ov2 = __shfl_xor(v2, m);
        int oi0 = __shfl_xor(i0, m), oi1 = __shfl_xor(i1, m),
            oi2 = __shfl_xor(i2, m);
        insM(ov0, oi0); insM(ov1, oi1); insM(ov2, oi2);
      }
    };

    int cxL = max(cx - 1, 0), cxH = min(cx + 1, GX - 1);
    int cyL = max(cy - 1, 0), cyH = min(cy + 1, GY - 1);
    for (int ry = cyL; ry <= cyH; ++ry) scanRow(ry, cxL, cxH);
    mergeAll();

    // ring expansion: rare (P ~ 8e-4/query at 4px cells) but exactness-
    // preserving. Computed-d2 skew bound <= 0.05 << 1.0 slack.
    while (true) {
      bool fullDom = (cxL == 0 && cxH == GX - 1 && cyL == 0 && cyH == GY - 1);
      float dL = (cxL > 0) ? (xf - (float)(cxL * 4)) : FBIG;
      float dR = (cxH < GX - 1) ? ((float)((cxH + 1) * 4) - xf) : FBIG;
      float dB = (cyL > 0) ? (yf - (float)(cyL * 4)) : FBIG;
      float dT = (cyH < GY - 1) ? ((float)((cyH + 1) * 4) - yf) : FBIG;
      float dmin = fminf(fminf(dL, dR), fminf(dB, dT));
      if (fullDom || (v2 < dmin * dmin - 1.0f)) break;
      int nxL = max(cxL - 1, 0), nxH = min(cxH + 1, GX - 1);
      int nyL = max(cyL - 1, 0), nyH = min(cyH + 1, GY - 1);
      for (int ry = nyL; ry <= nyH; ++ry) {
        if (ry < cyL || ry > cyH) scanRow(ry, nxL, nxH);
        else {
          if (nxL < cxL) scanRow(ry, nxL, cxL - 1);
          if (nxH > cxH) scanRow(ry, cxH + 1, nxH);
        }
      }
      cxL = nxL; cxH = nxH; cyL = nyL; cyH = nyH;
      mergeAll();
    }

    if (j == 0) { sidx[Q][0] = i0; sidx[Q][1] = i1; sidx[Q][2] = i2; }
  }
  __syncthreads();

  // ===== phase 1.5: cooperative h1 — lane o of query Q computes h1[k][o] ====
  {
    int Q = t >> 4;
    int o = t & 15;
    int qi = blockIdx.x * 16 + Q;
    float xf = (float)(qi % WW);
    float yf = (float)(qi / WW);
    float wa = w1[o * 3 + 0], wb = w1[o * 3 + 1], wc = w1[o * 3 + 2];
    float bo = b1[o];
#pragma unroll
    for (int k = 0; k < 3; ++k) {
      int i = sidx[Q][k];
      float u0 = uv[(size_t)b * 2 * NPTS + i];
      float u1 = uv[(size_t)b * 2 * NPTS + NPTS + i];
      float dx = u0 - xf;
      float dy = u1 - yf;
      float nrm = sqrtf(__builtin_fmaf(dx, dx, dy * dy));
      float h = fmaf(wa, dx, fmaf(wb, dy, fmaf(wc, nrm, bo)));
      sh1f[Q * 52 + k * 16 + o] = (h >= 0.0f) ? h : 0.1f * h;
    }
  }
  __syncthreads();

  // ===== phase 2: score + weighted feature sum (ql=t&15, cg=t>>4) ==========
  {
    int ql = t & 15;
    int cg = t >> 4;                 // channel group (4 ch)
    float h1a[3][16];
    {
      const float4* h4 = (const float4*)(sh1f + ql * 52);
#pragma unroll
      for (int i = 0; i < 12; ++i) {
        float4 v = h4[i];
        int k = i >> 2, oo = (i & 3) * 4;
        h1a[k][oo + 0] = v.x; h1a[k][oo + 1] = v.y;
        h1a[k][oo + 2] = v.z; h1a[k][oo + 3] = v.w;
      }
    }
    int idx[3] = {sidx[ql][0], sidx[ql][1], sidx[ql][2]};
    float4 f0 = *(const float4*)(f3dT + ((size_t)b * NPTS + idx[0]) * NC + cg * 4);
    float4 f1 = *(const float4*)(f3dT + ((size_t)b * NPTS + idx[1]) * NC + cg * 4);
    float4 f2 = *(const float4*)(f3dT + ((size_t)b * NPTS + idx[2]) * NC + cg * 4);
    float fa[4] = {f0.x, f0.y, f0.z, f0.w};
    float fb[4] = {f1.x, f1.y, f1.z, f1.w};
    float fc[4] = {f2.x, f2.y, f2.z, f2.w};
#pragma unroll
    for (int cc = 0; cc < 4; ++cc) {
      int c = cg * 4 + cc;
      float bias = b2[c];
      float s0 = bias, s1 = bias, s2 = bias;
      const float4* w2r = (const float4*)(w2 + c * 16);
#pragma unroll
      for (int o4 = 0; o4 < 4; ++o4) {
        float4 wv = w2r[o4];
        float wvs[4] = {wv.x, wv.y, wv.z, wv.w};
#pragma unroll
        for (int oo = 0; oo < 4; ++oo) {
          int o = o4 * 4 + oo;
          s0 = fmaf(wvs[oo], h1a[0][o], s0);
          s1 = fmaf(wvs[oo], h1a[1][o], s1);
          s2 = fmaf(wvs[oo], h1a[2][o], s2);
        }
      }
      float g0 = 1.0f / (1.0f + __expf(-s0));
      float g1 = 1.0f / (1.0f + __expf(-s1));
      float g2 = 1.0f / (1.0f + __expf(-s2));
      fin[ql][c] = fmaf(g0, fa[cc], fmaf(g1, fb[cc], g2 * fc[cc]));
    }
  }
  __syncthreads();

  // ===== phase B: out-projection, 4 output channels per thread =============
  {
    int qb = t & 15;
    int cgb = t >> 4;
    int q = blockIdx.x * 16 + qb;
    int o0 = cgb * 4;
    float acc[4];
#pragma unroll
    for (int jj = 0; jj < 4; ++jj) acc[jj] = b_out[o0 + jj];
    const float4* finq = (const float4*)(&fin[qb][0]);
#pragma unroll 4
    for (int c4 = 0; c4 < 16; ++c4) {
      float4 f = finq[c4];
#pragma unroll
      for (int jj = 0; jj < 4; ++jj) {
        float4 wv = *(const float4*)(w_out + (o0 + jj) * 64 + c4 * 4);
        acc[jj] = fmaf(wv.x, f.x,
                  fmaf(wv.y, f.y,
                  fmaf(wv.z, f.z,
                  fmaf(wv.w, f.w, acc[jj]))));
      }
    }
    float* dst = out + ((size_t)(b * 64 + o0)) * HW + q;
#pragma unroll
    for (int jj = 0; jj < 4; ++jj) {
      float v = acc[jj];
      dst[(size_t)jj * HW] = (v >= 0.0f) ? v : 0.1f * v;
    }
  }
}

extern "C" void kernel_launch(void* const* d_in, const int* in_sizes, int n_in,
                              void* d_out, int out_size, void* d_ws, size_t ws_size,
                              hipStream_t stream) {
  const float* uv   = (const float*)d_in[0];
  // d_in[1] = feat_2d : values unused by the reference (shape only)
  const float* f3d  = (const float*)d_in[2];
  const float* w1   = (const float*)d_in[3];
  const float* b1   = (const float*)d_in[4];
  const float* w2   = (const float*)d_in[5];
  const float* b2   = (const float*)d_in[6];
  const float* wout = (const float*)d_in[7];
  const float* bout = (const float*)d_in[8];
  float* out = (float*)d_out;

  char* ws = (char*)d_ws;
  float*  f3dT      = (float*)(ws);             // 2*4096*64*4 = 2097152 B
  float4* binned    = (float4*)(ws + 2097152);  // 2*4096*16   = 131072 B
  int*    cellStart = (int*)(ws + 2228224);     // 2*1024*4    = 8192 B
                                                // total ≈ 2.24 MB

  hipLaunchKernelGGL(k0_prep, dim3(258), dim3(256), 0, stream,
                     uv, f3d, f3dT, binned, cellStart);
  hipLaunchKernelGGL(k_main, dim3(HW / 16, NBS), dim3(256), 0, stream,
                     (const float4*)binned, (const int*)cellStart,
                     uv, f3dT, w1, b1, w2, b2, wout, bout, out);
}

// Round 16
// 45.562 us; speedup vs baseline: 1.2418x; 1.0358x over previous
//
#include <hip/hip_runtime.h>
#include <math.h>

#define NBS 2
#define NPTS 4096
#define HH 64
#define WW 192
#define HW (HH*WW)        // 12288
#define NC 64
#define GX 48             // cells in x (4 px each)
#define GY 16             // cells in y
#define NCELL (GX*GY)     // 768
#define CSB 1024          // cellStart stride per batch

#define FBIG 3.0e38f
#define IBIG 0x7FFFFFFF

// ---------------- K0: bin points (blocks 0-1) + transpose feat_3d -----------
__global__ __launch_bounds__(256) void k0_prep(
    const float* __restrict__ uv, const float* __restrict__ f3d,
    float* __restrict__ f3dT, float4* __restrict__ binned,
    int* __restrict__ cellStart) {
#pragma clang fp contract(off)
  int bid = blockIdx.x;
  int t = threadIdx.x;
  if (bid < 2) {
    // counting-sort bin for batch b (single block per batch)
    int b = bid;
    __shared__ int hist[NCELL];
    __shared__ int cum[NCELL];
    __shared__ int cur[NCELL];
    for (int c = t; c < NCELL; c += 256) hist[c] = 0;
    __syncthreads();
    const float* u0p = uv + (size_t)b * 2 * NPTS;
    const float* u1p = u0p + NPTS;
    for (int n = t; n < NPTS; n += 256) {
      float u0 = u0p[n], u1 = u1p[n];
      int cxp = min((int)(u0 * 0.25f), GX - 1);   // *0.25f exact (pow2)
      int cyp = min((int)(u1 * 0.25f), GY - 1);
      atomicAdd(&hist[cyp * GX + cxp], 1);
    }
    __syncthreads();
    // single-wave inclusive scan: 12 chunks of 64 + running carry
    if (t < 64) {
      int carry = 0;
#pragma unroll
      for (int ck = 0; ck < NCELL / 64; ++ck) {
        int v = hist[ck * 64 + t];
#pragma unroll
        for (int off = 1; off < 64; off <<= 1) {
          int u = __shfl_up(v, off);
          if (t >= off) v += u;
        }
        cum[ck * 64 + t] = v + carry;
        carry += __shfl(v, 63);
      }
    }
    __syncthreads();
    if (t == 0) cellStart[b * CSB] = 0;
    for (int c = t; c < NCELL; c += 256) {
      cellStart[b * CSB + c + 1] = cum[c];
      cur[c] = cum[c] - hist[c];            // exclusive start
    }
    __syncthreads();
    for (int n = t; n < NPTS; n += 256) {
      float u0 = u0p[n], u1 = u1p[n];
      // golden rounding: uu = rnd(rnd(u0^2)+rnd(u1^2)); contract(off) => no fma
      float s0 = u0 * u0;
      float s1 = u1 * u1;
      float uu = s0 + s1;
      int cxp = min((int)(u0 * 0.25f), GX - 1);
      int cyp = min((int)(u1 * 0.25f), GY - 1);
      int pos = atomicAdd(&cur[cyp * GX + cxp], 1);
      binned[(size_t)b * NPTS + pos] =
          make_float4(u0 + u0, u1 + u1, uu, __int_as_float(n));
    }
  } else {
    // transpose 64n x 32c half-tile: bb in [0,256)
    int bb = bid - 2;
    int b = bb >> 7;                       // batch
    int half = (bb >> 6) & 1;              // channel half
    int nt = (bb & 63) << 6;               // n tile base
    __shared__ float tile[32][65];
    int n_in = t & 63;
    int r0 = t >> 6;                       // 0..3
    const float* src = f3d + (size_t)b * NC * NPTS + (size_t)half * 32 * NPTS;
#pragma unroll
    for (int r = 0; r < 8; ++r) {
      int c = r0 + (r << 2);               // 0..31
      tile[c][n_in] = src[(size_t)c * NPTS + nt + n_in];
    }
    __syncthreads();
    float* dst = f3dT + ((size_t)b * NPTS + nt) * NC + half * 32;
    int c_out = t & 31;                    // 0..31
    int n0 = t >> 5;                       // 0..7
#pragma unroll
    for (int r = 0; r < 8; ++r) {
      int n = n0 + (r << 3);
      dst[(size_t)n * NC + c_out] = tile[c_out][n];
    }
  }
}

// ---------------- K_MAIN: fused binned 3-NN + MLP + out-projection ----------
// R15's 47.2 µs structure with: (1) batch-uniform SGPR bases + 32-bit offsets
// on all hot loads, (2) depth-3 interleaved window scan (lex selection is
// order-independent, so candidate reorder is bit-exact), (3) gathers issued
// before LDS unpack in phase 2.
__global__ __launch_bounds__(256) void k_main(
    const float4* __restrict__ binned, const int* __restrict__ cellStart,
    const float* __restrict__ uv, const float* __restrict__ f3dT,
    const float* __restrict__ w1, const float* __restrict__ b1,
    const float* __restrict__ w2, const float* __restrict__ b2,
    const float* __restrict__ w_out, const float* __restrict__ b_out,
    float* __restrict__ out) {
#pragma clang fp contract(off)
  int t = threadIdx.x;
  int b = blockIdx.y;

  // batch-uniform bases, hoisted once (SGPR); all hot offsets are 32-bit
  const float4* __restrict__ pts = binned + b * NPTS;
  const int* __restrict__ cs = cellStart + b * CSB;
  const float* __restrict__ uvb = uv + b * 2 * NPTS;
  const float* __restrict__ f3b = f3dT + (size_t)b * NPTS * NC;
  float* __restrict__ outb = out + (size_t)b * NC * HW;

  __shared__ int sidx[16][4];
  __shared__ float sh1f[16 * 52];  // h1[3][16] per query, 52-float row
  __shared__ float fin[16][68];    // row stride 272 B

  // ===== phase 1: KNN =====
  {
    int Q = t >> 4;                      // query slot 0..15
    int j = t & 15;                      // splitter lane
    int qi = blockIdx.x * 16 + Q;
    int x = qi % WW, y = qi / WW;
    float xf = (float)x, yf = (float)y;
    float gg = xf * xf + yf * yf;        // exact small ints
    int cx = x >> 2, cy = y >> 2;

    float v0 = FBIG, v1 = FBIG, v2 = FBIG;
    int i0 = IBIG, i1 = IBIG, i2 = IBIG;

    // dup-free lex (d,idx) sorted insert — scan candidates are distinct
    auto insS = [&](float d, int gi) {
      bool lt2 = (d < v2) || (d == v2 && gi < i2);
      bool lt1 = (d < v1) || (d == v1 && gi < i1);
      bool lt0 = (d < v0) || (d == v0 && gi < i0);
      i2 = lt1 ? i1 : (lt2 ? gi : i2);
      v2 = lt1 ? v1 : (lt2 ? d : v2);
      i1 = lt0 ? i0 : (lt1 ? gi : i1);
      v1 = lt0 ? v0 : (lt1 ? d : v1);
      i0 = lt0 ? gi : i0;
      v0 = lt0 ? d : v0;
    };
    // dup-safe variant for cross-lane merges (idempotent under repeats)
    auto insM = [&](float d, int gi) {
      bool dup = (gi == i0) || (gi == i1) || (gi == i2);
      bool lt2 = !dup && ((d < v2) || (d == v2 && gi < i2));
      bool lt1 = !dup && ((d < v1) || (d == v1 && gi < i1));
      bool lt0 = !dup && ((d < v0) || (d == v0 && gi < i0));
      i2 = lt1 ? i1 : (lt2 ? gi : i2);
      v2 = lt1 ? v1 : (lt2 ? d : v2);
      i1 = lt0 ? i0 : (lt1 ? gi : i1);
      v1 = lt0 ? v0 : (lt1 ? d : v1);
      i0 = lt0 ? gi : i0;
      v0 = lt0 ? d : v0;
    };
    auto scanRow = [&](int ry, int cA, int cB) {   // ring fallback (rare)
      int s = cs[ry * GX + cA];
      int e = cs[ry * GX + cB + 1];
      for (int n = s + j; n < e; n += 16) {
        float4 p = pts[n];
        float d = (gg + p.z) - __builtin_fmaf(yf, p.y, xf * p.x);
        insS(d, __float_as_int(p.w));
      }
    };
    auto mergeAll = [&]() {
#pragma unroll
      for (int m = 1; m <= 8; m <<= 1) {
        float ov0 = __shfl_xor(v0, m), ov1 = __shfl_xor(v1, m),
              ov2 = __shfl_xor(v2, m);
        int oi0 = __shfl_xor(i0, m), oi1 = __shfl_xor(i1, m),
            oi2 = __shfl_xor(i2, m);
        insM(ov0, oi0); insM(ov1, oi1); insM(ov2, oi2);
      }
    };

    int cxL = max(cx - 1, 0), cxH = min(cx + 1, GX - 1);
    int cyL = max(cy - 1, 0), cyH = min(cy + 1, GY - 1);

    // depth-3 interleaved window scan: rows' loads are independent.
    // Lex (d,idx) selection is order-independent => bit-identical result.
    {
      int nrows = cyH - cyL + 1;
      int r0s = cs[cyL * GX + cxL];
      int r0e = cs[cyL * GX + cxH + 1];
      int r1s = 0, r1e = 0, r2s = 0, r2e = 0;
      if (nrows > 1) {
        r1s = cs[(cyL + 1) * GX + cxL];
        r1e = cs[(cyL + 1) * GX + cxH + 1];
      }
      if (nrows > 2) {
        r2s = cs[(cyL + 2) * GX + cxL];
        r2e = cs[(cyL + 2) * GX + cxH + 1];
      }
      int n0 = r0s + j, n1 = r1s + j, n2 = r2s + j;
      for (;;) {
        bool a0 = n0 < r0e, a1 = n1 < r1e, a2 = n2 < r2e;
        if (!(a0 || a1 || a2)) break;
        float4 p0, p1, p2;
        if (a0) p0 = pts[n0];
        if (a1) p1 = pts[n1];
        if (a2) p2 = pts[n2];
        if (a0) {
          float d = (gg + p0.z) - __builtin_fmaf(yf, p0.y, xf * p0.x);
          insS(d, __float_as_int(p0.w));
          n0 += 16;
        }
        if (a1) {
          float d = (gg + p1.z) - __builtin_fmaf(yf, p1.y, xf * p1.x);
          insS(d, __float_as_int(p1.w));
          n1 += 16;
        }
        if (a2) {
          float d = (gg + p2.z) - __builtin_fmaf(yf, p2.y, xf * p2.x);
          insS(d, __float_as_int(p2.w));
          n2 += 16;
        }
      }
    }
    mergeAll();

    // ring expansion: rare (P ~ 8e-4/query at 4px cells) but exactness-
    // preserving. Computed-d2 skew bound <= 0.05 << 1.0 slack.
    while (true) {
      bool fullDom = (cxL == 0 && cxH == GX - 1 && cyL == 0 && cyH == GY - 1);
      float dL = (cxL > 0) ? (xf - (float)(cxL * 4)) : FBIG;
      float dR = (cxH < GX - 1) ? ((float)((cxH + 1) * 4) - xf) : FBIG;
      float dB = (cyL > 0) ? (yf - (float)(cyL * 4)) : FBIG;
      float dT = (cyH < GY - 1) ? ((float)((cyH + 1) * 4) - yf) : FBIG;
      float dmin = fminf(fminf(dL, dR), fminf(dB, dT));
      if (fullDom || (v2 < dmin * dmin - 1.0f)) break;
      int nxL = max(cxL - 1, 0), nxH = min(cxH + 1, GX - 1);
      int nyL = max(cyL - 1, 0), nyH = min(cyH + 1, GY - 1);
      for (int ry = nyL; ry <= nyH; ++ry) {
        if (ry < cyL || ry > cyH) scanRow(ry, nxL, nxH);
        else {
          if (nxL < cxL) scanRow(ry, nxL, cxL - 1);
          if (nxH > cxH) scanRow(ry, cxH + 1, nxH);
        }
      }
      cxL = nxL; cxH = nxH; cyL = nyL; cyH = nyH;
      mergeAll();
    }

    if (j == 0) { sidx[Q][0] = i0; sidx[Q][1] = i1; sidx[Q][2] = i2; }
  }
  __syncthreads();

  // ===== phase 1.5: cooperative h1 — lane o of query Q computes h1[k][o] ====
  {
    int Q = t >> 4;
    int o = t & 15;
    int qi = blockIdx.x * 16 + Q;
    float xf = (float)(qi % WW);
    float yf = (float)(qi / WW);
    float wa = w1[o * 3 + 0], wb = w1[o * 3 + 1], wc = w1[o * 3 + 2];
    float bo = b1[o];
#pragma unroll
    for (int k = 0; k < 3; ++k) {
      int i = sidx[Q][k];
      float u0 = uvb[i];
      float u1 = uvb[NPTS + i];
      float dx = u0 - xf;
      float dy = u1 - yf;
      float nrm = sqrtf(__builtin_fmaf(dx, dx, dy * dy));
      float h = fmaf(wa, dx, fmaf(wb, dy, fmaf(wc, nrm, bo)));
      sh1f[Q * 52 + k * 16 + o] = (h >= 0.0f) ? h : 0.1f * h;
    }
  }
  __syncthreads();

  // ===== phase 2: score + weighted feature sum (ql=t&15, cg=t>>4) ==========
  {
    int ql = t & 15;
    int cg = t >> 4;                 // channel group (4 ch)
    int idx[3] = {sidx[ql][0], sidx[ql][1], sidx[ql][2]};
    // issue the gathers first (independent of the LDS unpack below)
    float4 f0 = *(const float4*)(f3b + idx[0] * NC + cg * 4);
    float4 f1 = *(const float4*)(f3b + idx[1] * NC + cg * 4);
    float4 f2 = *(const float4*)(f3b + idx[2] * NC + cg * 4);
    float h1a[3][16];
    {
      const float4* h4 = (const float4*)(sh1f + ql * 52);
#pragma unroll
      for (int i = 0; i < 12; ++i) {
        float4 v = h4[i];
        int k = i >> 2, oo = (i & 3) * 4;
        h1a[k][oo + 0] = v.x; h1a[k][oo + 1] = v.y;
        h1a[k][oo + 2] = v.z; h1a[k][oo + 3] = v.w;
      }
    }
    float fa[4] = {f0.x, f0.y, f0.z, f0.w};
    float fb[4] = {f1.x, f1.y, f1.z, f1.w};
    float fc[4] = {f2.x, f2.y, f2.z, f2.w};
#pragma unroll
    for (int cc = 0; cc < 4; ++cc) {
      int c = cg * 4 + cc;
      float bias = b2[c];
      float s0 = bias, s1 = bias, s2 = bias;
      const float4* w2r = (const float4*)(w2 + c * 16);
#pragma unroll
      for (int o4 = 0; o4 < 4; ++o4) {
        float4 wv = w2r[o4];
        float wvs[4] = {wv.x, wv.y, wv.z, wv.w};
#pragma unroll
        for (int oo = 0; oo < 4; ++oo) {
          int o = o4 * 4 + oo;
          s0 = fmaf(wvs[oo], h1a[0][o], s0);
          s1 = fmaf(wvs[oo], h1a[1][o], s1);
          s2 = fmaf(wvs[oo], h1a[2][o], s2);
        }
      }
      float g0 = 1.0f / (1.0f + __expf(-s0));
      float g1 = 1.0f / (1.0f + __expf(-s1));
      float g2 = 1.0f / (1.0f + __expf(-s2));
      fin[ql][c] = fmaf(g0, fa[cc], fmaf(g1, fb[cc], g2 * fc[cc]));
    }
  }
  __syncthreads();

  // ===== phase B: out-projection, 4 output channels per thread =============
  {
    int qb = t & 15;
    int cgb = t >> 4;
    int q = blockIdx.x * 16 + qb;
    int o0 = cgb * 4;
    float acc[4];
#pragma unroll
    for (int jj = 0; jj < 4; ++jj) acc[jj] = b_out[o0 + jj];
    const float4* finq = (const float4*)(&fin[qb][0]);
#pragma unroll 4
    for (int c4 = 0; c4 < 16; ++c4) {
      float4 f = finq[c4];
#pragma unroll
      for (int jj = 0; jj < 4; ++jj) {
        float4 wv = *(const float4*)(w_out + (o0 + jj) * 64 + c4 * 4);
        acc[jj] = fmaf(wv.x, f.x,
                  fmaf(wv.y, f.y,
                  fmaf(wv.z, f.z,
                  fmaf(wv.w, f.w, acc[jj]))));
      }
    }
    float* dst = outb + o0 * HW + q;
#pragma unroll
    for (int jj = 0; jj < 4; ++jj) {
      float v = acc[jj];
      dst[jj * HW] = (v >= 0.0f) ? v : 0.1f * v;
    }
  }
}

extern "C" void kernel_launch(void* const* d_in, const int* in_sizes, int n_in,
                              void* d_out, int out_size, void* d_ws, size_t ws_size,
                              hipStream_t stream) {
  const float* uv   = (const float*)d_in[0];
  // d_in[1] = feat_2d : values unused by the reference (shape only)
  const float* f3d  = (const float*)d_in[2];
  const float* w1   = (const float*)d_in[3];
  const float* b1   = (const float*)d_in[4];
  const float* w2   = (const float*)d_in[5];
  const float* b2   = (const float*)d_in[6];
  const float* wout = (const float*)d_in[7];
  const float* bout = (const float*)d_in[8];
  float* out = (float*)d_out;

  char* ws = (char*)d_ws;
  float*  f3dT      = (float*)(ws);             // 2*4096*64*4 = 2097152 B
  float4* binned    = (float4*)(ws + 2097152);  // 2*4096*16   = 131072 B
  int*    cellStart = (int*)(ws + 2228224);     // 2*1024*4    = 8192 B
                                                // total ≈ 2.24 MB

  hipLaunchKernelGGL(k0_prep, dim3(258), dim3(256), 0, stream,
                     uv, f3d, f3dT, binned, cellStart);
  hipLaunchKernelGGL(k_main, dim3(HW / 16, NBS), dim3(256), 0, stream,
                     (const float4*)binned, (const int*)cellStart,
                     uv, f3dT, w1, b1, w2, b2, wout, bout, out);
}